// Round 12
// baseline (469.055 us; speedup 1.0000x reference)
//
#include <hip/hip_runtime.h>

#define BLOCK 256
#define REP 3   // DIAGNOSTIC: run the full work 3x so the edge kernel exceeds the
                // rocprof top-5 cutoff (~150us) and surfaces its own counters.
                // Reps 0/1 use perturbed in-block indices (distinct values, same
                // cache lines, no CSE); final rep computes/stores correct values.

typedef float vf4 __attribute__((ext_vector_type(4)));

// Prepass: pack (pos.xyz, bitcast(batch)) into a 16B-aligned float4 table.
extern "C" __global__ void __launch_bounds__(BLOCK) pack_pos_batch(
    const float* __restrict__ pos,      // [N,3]
    const int*  __restrict__ batch,     // [N]
    vf4* __restrict__ pos4,             // [N] out
    int N)
{
    const int i = blockIdx.x * BLOCK + threadIdx.x;
    if (i < N) {
        vf4 v;
        v.x = pos[3 * i + 0];
        v.y = pos[3 * i + 1];
        v.z = pos[3 * i + 2];
        v.w = __int_as_float(batch[i]);
        pos4[i] = v;
    }
}

template <bool PACKED>
__global__ void __launch_bounds__(BLOCK) edge_encoding_kernel(
    const float* __restrict__ pos,      // [N,3] (fallback)
    const vf4*   __restrict__ pos4,     // [N] packed
    const float* __restrict__ cells,    // [G,3,3] = 144 f32
    const int*   __restrict__ eidx,     // [2,E]
    const int*   __restrict__ pidx,     // [E]
    const int*   __restrict__ batch,    // [N] (fallback)
    float* __restrict__ out,            // [E,19]
    int E)
{
    __shared__ float s_cells[144];
    __shared__ __align__(16) float s_out[BLOCK * 19];   // 19456 B

    const int tid = threadIdx.x;
    if (tid < 144) s_cells[tid] = cells[tid];
    __syncthreads();

    const int base = blockIdx.x * BLOCK;

    #pragma unroll 1
    for (int rep = 0; rep < REP; ++rep) {
        // rep 0 -> tid^1, rep 1 -> tid^2, final rep -> tid (correct)
        const int perturb = (rep == REP - 1) ? 0 : (rep + 1);
        const int e_true  = base + tid;
        int e = base + (tid ^ perturb);
        if (e >= E) e = E - 1;            // clamped rows overwritten by final rep

        float row[19];
        if (e_true < E || perturb != 0) {
            const int src = __builtin_nontemporal_load(eidx + e);
            const int dst = __builtin_nontemporal_load(eidx + E + e);
            const int p   = __builtin_nontemporal_load(pidx + e);

            float sx, sy, sz, dx, dy, dz;
            int g;
            if (PACKED) {
                const vf4 ps = pos4[src];
                const vf4 pd = pos4[dst];
                sx = ps.x; sy = ps.y; sz = ps.z;
                dx = pd.x; dy = pd.y; dz = pd.z;
                g  = __float_as_int(ps.w);
            } else {
                sx = pos[3*src+0]; sy = pos[3*src+1]; sz = pos[3*src+2];
                dx = pos[3*dst+0]; dy = pos[3*dst+1]; dz = pos[3*dst+2];
                g  = batch[src];
            }

            // periodic shift: p = i*9 + j*3 + k -> (i-1, j-1, k-1)
            const float f0 = (float)(p / 9 - 1);
            const float f1 = (float)((p / 3) % 3 - 1);
            const float f2 = (float)(p % 3 - 1);

            const float* C = s_cells + g * 9;
            const float tx = C[0]*f0 + C[3]*f1 + C[6]*f2;
            const float ty = C[1]*f0 + C[4]*f1 + C[7]*f2;
            const float tz = C[2]*f0 + C[5]*f1 + C[8]*f2;

            const float vx = sx - dx + tx;
            const float vy = sy - dy + ty;
            const float vz = sz - dz + tz;

            const float len  = sqrtf(vx*vx + vy*vy + vz*vz);
            const float invl = __builtin_amdgcn_rcpf(fmaxf(len, 1e-6f));
            const float x = vx * invl, y = vy * invl, z = vz * invl;

            const float s3  = 1.7320508075688772f;
            const float s5  = 2.2360679774997896f;
            const float s15 = 3.872983346207417f;

            row[0] = len;
            row[1] = 1.0f;
            row[2] = s3 * x;
            row[3] = s3 * y;
            row[4] = s3 * z;
            row[5] = s15 * x * z;
            row[6] = s15 * x * y;
            row[7] = s5  * (y*y - 0.5f*(x*x + z*z));
            row[8] = s15 * y * z;
            row[9] = 0.5f * s15 * (z*z - x*x);

            // polynomial cutoff (P=6): 1 - 28 x^6 + 48 x^7 - 21 x^8
            const float xc = fminf(len * (1.0f/6.0f), 1.0f);
            const float x3 = xc * xc * xc;
            const float x6 = x3 * x3;
            const float cut = fmaf(x6, fmaf(xc, fmaf(-21.0f, xc, 48.0f), -28.0f), 1.0f);
            row[10] = cut;

            // bessel via Chebyshev; native sin/cos (~1e-5 err, tol 0.125)
            const float safe = fminf(fmaxf(len, 1e-6f), 6.0f);
            const float a = safe * 0.5235987755982988f;   // pi/6
            const float sa = __sinf(a);
            const float ca = __cosf(a);
            const float w = cut * 0.5f * __builtin_amdgcn_rcpf(safe);
            const float two_ca = 2.0f * ca;
            float s_prev = 0.0f, s_cur = sa;
            row[11] = s_cur * w;
            #pragma unroll
            for (int n = 2; n <= 8; ++n) {
                const float s_next = two_ca * s_cur - s_prev;
                s_prev = s_cur;
                s_cur  = s_next;
                row[10 + n] = s_cur * w;
            }
        } else {
            #pragma unroll
            for (int j = 0; j < 19; ++j) row[j] = 0.0f;
        }

        if (rep > 0) __syncthreads();    // prev copyout reads done before restage

        // stride-19 staging: gcd(19,32)=1 -> max 2 lanes/bank (free)
        #pragma unroll
        for (int j = 0; j < 19; ++j) s_out[tid * 19 + j] = row[j];
        __syncthreads();

        // coalesced copyout: wave-consecutive float4s = full 64B lines
        const int nvalid  = min(BLOCK, E - base);
        const int nfloats = nvalid * 19;
        float* gout = out + (size_t)base * 19;        // 19456B multiple: 16B aligned
        const int n4 = nfloats >> 2;
        const vf4* s4 = reinterpret_cast<const vf4*>(s_out);
        vf4* g4 = reinterpret_cast<vf4*>(gout);
        for (int i = tid; i < n4; i += BLOCK)
            __builtin_nontemporal_store(s4[i], g4 + i);
        for (int i = (n4 << 2) + tid; i < nfloats; i += BLOCK)
            __builtin_nontemporal_store(s_out[i], gout + i);

        asm volatile("" ::: "memory");   // no-op; blocks dead-store elimination across reps
    }
}

extern "C" void kernel_launch(void* const* d_in, const int* in_sizes, int n_in,
                              void* d_out, int out_size, void* d_ws, size_t ws_size,
                              hipStream_t stream) {
    const float* pos   = (const float*)d_in[0];
    const float* cells = (const float*)d_in[1];
    const int*   eidx  = (const int*)d_in[2];
    const int*   pidx  = (const int*)d_in[3];
    const int*   batch = (const int*)d_in[4];
    float* out = (float*)d_out;

    const int E = in_sizes[3];   // periodic_index count = num edges
    const int N = in_sizes[4];   // batch count = num nodes
    const int grid = (E + BLOCK - 1) / BLOCK;

    if (d_ws != nullptr && ws_size >= (size_t)N * sizeof(vf4)) {
        vf4* pos4 = (vf4*)d_ws;
        const int pgrid = (N + BLOCK - 1) / BLOCK;
        pack_pos_batch<<<pgrid, BLOCK, 0, stream>>>(pos, batch, pos4, N);
        edge_encoding_kernel<true><<<grid, BLOCK, 0, stream>>>(
            pos, pos4, cells, eidx, pidx, batch, out, E);
    } else {
        edge_encoding_kernel<false><<<grid, BLOCK, 0, stream>>>(
            pos, nullptr, cells, eidx, pidx, batch, out, E);
    }
}

// Round 13
// 324.012 us; speedup vs baseline: 1.4476x; 1.4476x over previous
//
#include <hip/hip_runtime.h>

#define BLOCK 256
#define WPB 4                 // waves per block
#define TILE_E 64             // edges per wave-tile
#define WREG (TILE_E * 19)    // 4864 B wave-private staging region

typedef float vf4 __attribute__((ext_vector_type(4)));

// Prepass: pack (pos.xyz, bitcast(batch)) into a 16B-aligned float4 table.
extern "C" __global__ void __launch_bounds__(BLOCK) pack_pos_batch(
    const float* __restrict__ pos,      // [N,3]
    const int*  __restrict__ batch,     // [N]
    vf4* __restrict__ pos4,             // [N] out
    int N)
{
    const int i = blockIdx.x * BLOCK + threadIdx.x;
    if (i < N) {
        vf4 v;
        v.x = pos[3 * i + 0];
        v.y = pos[3 * i + 1];
        v.z = pos[3 * i + 2];
        v.w = __int_as_float(batch[i]);
        pos4[i] = v;
    }
}

// Persistent wave-private pipelined kernel:
//  - NO barriers after prologue -> no vmcnt(0) drains -> prefetch survives
//  - per iteration: gather(t+1) | idx(t+2) | compute(t) | stage+copyout(t)
//  - gathers are consumed one full iteration after issue (latency hidden)
// __launch_bounds__(256,8): force VGPR<=64 so LDS (20032B -> 8 blk/CU) stays binding.
template <bool PACKED>
__global__ void __launch_bounds__(BLOCK, 8) edge_encoding_kernel(
    const float* __restrict__ pos,      // [N,3] (fallback)
    const vf4*   __restrict__ pos4,     // [N] packed
    const float* __restrict__ cells,    // [G,3,3] = 144 f32
    const int*   __restrict__ eidx,     // [2,E]
    const int*   __restrict__ pidx,     // [E]
    const int*   __restrict__ batch,    // [N] (fallback)
    float* __restrict__ out,            // [E,19]
    int E)
{
    __shared__ float s_cells[144];                      // 576 B
    __shared__ __align__(64) float s_out[WPB * WREG];   // 19456 B (4 wave regions)

    const int tid = threadIdx.x;
    if (tid < 144) s_cells[tid] = cells[tid];
    __syncthreads();   // ONLY barrier; nothing in VMEM flight yet

    const int lane = tid & 63;
    const int wid  = tid >> 6;
    float* s_buf = s_out + wid * WREG;

    const int ntiles = (E + TILE_E - 1) / TILE_E;
    const int nwaves = gridDim.x * WPB;
    int t = blockIdx.x * WPB + wid;
    if (t >= ntiles) return;            // wave-uniform exit (after barrier)

    const float s3  = 1.7320508075688772f;
    const float s5  = 2.2360679774997896f;
    const float s15 = 3.872983346207417f;

    // ---- pipeline state: idx for t+1, gathers for t (then t+1) ----
    int s0, d0, p0, s1, d1, p1;
    vf4 a0, b0;

    auto load_idx = [&](int tt, int& s, int& d, int& p) {
        if (tt < ntiles) {
            long long e = (long long)tt * TILE_E + lane;
            if (e >= E) e = E - 1;      // clamped rows are never copied out
            s = __builtin_nontemporal_load(eidx + e);
            d = __builtin_nontemporal_load(eidx + E + e);
            p = __builtin_nontemporal_load(pidx + e);
        } else { s = 0; d = 0; p = 13; }
    };
    auto do_gather = [&](int s, int d, vf4& a, vf4& b) {
        if (PACKED) {
            a = pos4[s];
            b = pos4[d];
        } else {
            a.x = pos[3*s+0]; a.y = pos[3*s+1]; a.z = pos[3*s+2];
            a.w = __int_as_float(batch[s]);
            b.x = pos[3*d+0]; b.y = pos[3*d+1]; b.z = pos[3*d+2];
            b.w = 0.0f;
        }
    };

    // prologue: fill the pipe (gather(t) latency exposed exactly once)
    load_idx(t, s0, d0, p0);
    do_gather(s0, d0, a0, b0);
    load_idx(t + nwaves, s1, d1, p1);

    for (; t < ntiles; t += nwaves) {
        // [A] issue next tile's gathers (idx loaded one iteration ago)
        vf4 a1, b1;
        do_gather(s1, d1, a1, b1);
        // [B] issue idx loads for tile t+2
        int s2, d2, p2;
        load_idx(t + 2 * nwaves, s2, d2, p2);

        // [C] compute tile t from gathers issued a full iteration ago
        float row[19];
        {
            const int g = __float_as_int(a0.w);
            const int p = p0;
            const float f0 = (float)(p / 9 - 1);
            const float f1 = (float)((p / 3) % 3 - 1);
            const float f2 = (float)(p % 3 - 1);

            const float* C = s_cells + g * 9;
            const float tx = C[0]*f0 + C[3]*f1 + C[6]*f2;
            const float ty = C[1]*f0 + C[4]*f1 + C[7]*f2;
            const float tz = C[2]*f0 + C[5]*f1 + C[8]*f2;

            const float vx = a0.x - b0.x + tx;
            const float vy = a0.y - b0.y + ty;
            const float vz = a0.z - b0.z + tz;

            const float len  = sqrtf(vx*vx + vy*vy + vz*vz);
            const float invl = __builtin_amdgcn_rcpf(fmaxf(len, 1e-6f));
            const float x = vx * invl, y = vy * invl, z = vz * invl;

            row[0] = len;
            row[1] = 1.0f;
            row[2] = s3 * x;
            row[3] = s3 * y;
            row[4] = s3 * z;
            row[5] = s15 * x * z;
            row[6] = s15 * x * y;
            row[7] = s5  * (y*y - 0.5f*(x*x + z*z));
            row[8] = s15 * y * z;
            row[9] = 0.5f * s15 * (z*z - x*x);

            // polynomial cutoff (P=6): 1 - 28 x^6 + 48 x^7 - 21 x^8
            const float xc = fminf(len * (1.0f/6.0f), 1.0f);
            const float x3 = xc * xc * xc;
            const float x6 = x3 * x3;
            const float cut = fmaf(x6, fmaf(xc, fmaf(-21.0f, xc, 48.0f), -28.0f), 1.0f);
            row[10] = cut;

            // bessel via Chebyshev recurrence; native sin/cos (~1e-5 err, tol 0.125)
            const float safe = fminf(fmaxf(len, 1e-6f), 6.0f);
            const float a = safe * 0.5235987755982988f;   // pi/6
            const float sa = __sinf(a);
            const float ca = __cosf(a);
            const float w = cut * 0.5f * __builtin_amdgcn_rcpf(safe);
            const float two_ca = 2.0f * ca;
            float s_prev = 0.0f, s_cur = sa;
            row[11] = s_cur * w;
            #pragma unroll
            for (int n = 2; n <= 8; ++n) {
                const float s_next = two_ca * s_cur - s_prev;
                s_prev = s_cur;
                s_cur  = s_next;
                row[10 + n] = s_cur * w;
            }
        }

        // [D] stage (stride-19: 2 lanes/bank, free) + wave-private copyout.
        // Wave-internal ds ordering via lgkmcnt; stores never block (no barrier).
        #pragma unroll
        for (int j = 0; j < 19; ++j) s_buf[lane * 19 + j] = row[j];

        const long long e0 = (long long)t * TILE_E;
        const int nvalid = (int)(((long long)E - e0) < TILE_E ? (E - e0) : TILE_E);
        float* gout = out + e0 * 19;
        if (nvalid == TILE_E) {
            const vf4* s4 = reinterpret_cast<const vf4*>(s_buf);
            vf4* g4 = reinterpret_cast<vf4*>(gout);
            #pragma unroll
            for (int i = lane; i < 304; i += 64)     // 304 vf4 = 4864 B, full lines
                g4[i] = s4[i];
        } else {
            const int nf = nvalid * 19;
            for (int i = lane; i < nf; i += 64)
                gout[i] = s_buf[i];
        }

        // rotate pipeline
        a0 = a1; b0 = b1; p0 = p1;
        s1 = s2; d1 = d2; p1 = p2;
    }
}

extern "C" void kernel_launch(void* const* d_in, const int* in_sizes, int n_in,
                              void* d_out, int out_size, void* d_ws, size_t ws_size,
                              hipStream_t stream) {
    const float* pos   = (const float*)d_in[0];
    const float* cells = (const float*)d_in[1];
    const int*   eidx  = (const int*)d_in[2];
    const int*   pidx  = (const int*)d_in[3];
    const int*   batch = (const int*)d_in[4];
    float* out = (float*)d_out;

    const int E = in_sizes[3];   // periodic_index count = num edges
    const int N = in_sizes[4];   // batch count = num nodes
    const int ntiles = (E + TILE_E - 1) / TILE_E;
    int grid = (ntiles + WPB - 1) / WPB;
    if (grid > 2048) grid = 2048;    // 8 blocks/CU resident; waves grid-stride

    if (d_ws != nullptr && ws_size >= (size_t)N * sizeof(vf4)) {
        vf4* pos4 = (vf4*)d_ws;
        const int pgrid = (N + BLOCK - 1) / BLOCK;
        pack_pos_batch<<<pgrid, BLOCK, 0, stream>>>(pos, batch, pos4, N);
        edge_encoding_kernel<true><<<grid, BLOCK, 0, stream>>>(
            pos, pos4, cells, eidx, pidx, batch, out, E);
    } else {
        edge_encoding_kernel<false><<<grid, BLOCK, 0, stream>>>(
            pos, nullptr, cells, eidx, pidx, batch, out, E);
    }
}

// Round 14
// 294.030 us; speedup vs baseline: 1.5953x; 1.1020x over previous
//
#include <hip/hip_runtime.h>

#define BLOCK 256

// clang-native vector type: accepted by __builtin_nontemporal_{load,store}
typedef float vf4 __attribute__((ext_vector_type(4)));

// Prepass: pack (pos.xyz, bitcast(batch)) into a 16B-aligned float4 table.
// Turns 7 scalar gather instructions/edge into 2 aligned dwordx4 gathers.
extern "C" __global__ void __launch_bounds__(BLOCK) pack_pos_batch(
    const float* __restrict__ pos,      // [N,3]
    const int*  __restrict__ batch,     // [N]
    vf4* __restrict__ pos4,             // [N] out
    int N)
{
    const int i = blockIdx.x * BLOCK + threadIdx.x;
    if (i < N) {
        vf4 v;
        v.x = pos[3 * i + 0];
        v.y = pos[3 * i + 1];
        v.z = pos[3 * i + 2];
        v.w = __int_as_float(batch[i]);
        pos4[i] = v;
    }
}

template <bool PACKED>
__global__ void __launch_bounds__(BLOCK) edge_encoding_kernel(
    const float* __restrict__ pos,      // [N,3] f32 (fallback path)
    const vf4*   __restrict__ pos4,     // [N] packed (PACKED path)
    const float* __restrict__ cells,    // [G,3,3] = 144 f32
    const int*   __restrict__ eidx,     // [2,E]
    const int*   __restrict__ pidx,     // [E]
    const int*   __restrict__ batch,    // [N] (fallback path)
    float* __restrict__ out,            // [E,19] f32
    int E)
{
    __shared__ float s_cells[144];
    __shared__ __align__(16) float s_out[BLOCK * 19];   // 19456 B

    const int tid = threadIdx.x;
    if (tid < 144) s_cells[tid] = cells[tid];
    __syncthreads();

    const int base = blockIdx.x * BLOCK;
    const int e = base + tid;

    float row[19];
    if (e < E) {
        // streamed once -> nontemporal: don't churn L2 (preserve pos4 residency)
        const int src = __builtin_nontemporal_load(eidx + e);
        const int dst = __builtin_nontemporal_load(eidx + E + e);
        const int p   = __builtin_nontemporal_load(pidx + e);

        float sx, sy, sz, dx, dy, dz;
        int g;
        if (PACKED) {
            // one 64B-line gather per endpoint (16B aligned, never straddles)
            const vf4 ps = pos4[src];
            const vf4 pd = pos4[dst];
            sx = ps.x; sy = ps.y; sz = ps.z;
            dx = pd.x; dy = pd.y; dz = pd.z;
            g  = __float_as_int(ps.w);
        } else {
            sx = pos[3*src+0]; sy = pos[3*src+1]; sz = pos[3*src+2];
            dx = pos[3*dst+0]; dy = pos[3*dst+1]; dz = pos[3*dst+2];
            g  = batch[src];
        }

        // periodic shift from index: p = i*9 + j*3 + k -> (i-1, j-1, k-1)
        const float f0 = (float)(p / 9 - 1);
        const float f1 = (float)((p / 3) % 3 - 1);
        const float f2 = (float)(p % 3 - 1);

        const float* C = s_cells + g * 9;
        // t_j = sum_i cell[i][j] * shift[i]
        const float tx = C[0]*f0 + C[3]*f1 + C[6]*f2;
        const float ty = C[1]*f0 + C[4]*f1 + C[7]*f2;
        const float tz = C[2]*f0 + C[5]*f1 + C[8]*f2;

        // v = -(pos[dst]-pos[src] - t) = pos[src] - pos[dst] + t
        const float vx = sx - dx + tx;
        const float vy = sy - dy + ty;
        const float vz = sz - dz + tz;

        const float len  = sqrtf(vx*vx + vy*vy + vz*vz);
        const float invl = 1.0f / fmaxf(len, 1e-6f);
        const float x = vx * invl, y = vy * invl, z = vz * invl;

        const float s3  = 1.7320508075688772f;
        const float s5  = 2.2360679774997896f;
        const float s15 = 3.872983346207417f;

        row[0] = len;
        row[1] = 1.0f;
        row[2] = s3 * x;
        row[3] = s3 * y;
        row[4] = s3 * z;
        row[5] = s15 * x * z;
        row[6] = s15 * x * y;
        row[7] = s5  * (y*y - 0.5f*(x*x + z*z));
        row[8] = s15 * y * z;
        row[9] = 0.5f * s15 * (z*z - x*x);

        // polynomial cutoff (P=6): 1 - 28 x^6 + 48 x^7 - 21 x^8
        const float xc = fminf(len * (1.0f/6.0f), 1.0f);
        const float x3 = xc * xc * xc;
        const float x6 = x3 * x3;
        const float cut = fmaf(x6, fmaf(xc, fmaf(-21.0f, xc, 48.0f), -28.0f), 1.0f);
        row[10] = cut;

        // bessel: sin(n*a)/(2*safe) * cut, a = safe*pi/6, n=1..8 (Chebyshev recurrence)
        // native v_sin/v_cos: ~1e-5 abs err, tolerance is 0.125 -> safe
        const float safe = fminf(fmaxf(len, 1e-6f), 6.0f);
        const float a = safe * 0.5235987755982988f;   // pi/6
        const float sa = __sinf(a);
        const float ca = __cosf(a);
        const float w = cut / (2.0f * safe);
        const float two_ca = 2.0f * ca;
        float s_prev = 0.0f, s_cur = sa;
        row[11] = s_cur * w;
        #pragma unroll
        for (int n = 2; n <= 8; ++n) {
            const float s_next = two_ca * s_cur - s_prev;
            s_prev = s_cur;
            s_cur  = s_next;
            row[10 + n] = s_cur * w;
        }
    } else {
        #pragma unroll
        for (int j = 0; j < 19; ++j) row[j] = 0.0f;
    }

    // stride-19 writes: gcd(19,32)=1 -> bank-conflict-free
    #pragma unroll
    for (int j = 0; j < 19; ++j) s_out[tid * 19 + j] = row[j];
    __syncthreads();

    // coalesced copy LDS -> global in float4 chunks, nontemporal (write-once stream)
    const int nvalid  = min(BLOCK, E - base);
    const int nfloats = nvalid * 19;
    float* gout = out + (size_t)base * 19;            // 19456-byte multiple: 16B aligned
    const int n4 = nfloats >> 2;
    const vf4* s4 = reinterpret_cast<const vf4*>(s_out);
    vf4* g4 = reinterpret_cast<vf4*>(gout);
    for (int i = tid; i < n4; i += BLOCK)
        __builtin_nontemporal_store(s4[i], g4 + i);
    for (int i = (n4 << 2) + tid; i < nfloats; i += BLOCK)
        __builtin_nontemporal_store(s_out[i], gout + i);
}

extern "C" void kernel_launch(void* const* d_in, const int* in_sizes, int n_in,
                              void* d_out, int out_size, void* d_ws, size_t ws_size,
                              hipStream_t stream) {
    const float* pos   = (const float*)d_in[0];
    const float* cells = (const float*)d_in[1];
    const int*   eidx  = (const int*)d_in[2];
    const int*   pidx  = (const int*)d_in[3];
    const int*   batch = (const int*)d_in[4];
    float* out = (float*)d_out;

    const int E = in_sizes[3];   // periodic_index count = num edges
    const int N = in_sizes[4];   // batch count = num nodes
    const int grid = (E + BLOCK - 1) / BLOCK;

    if (d_ws != nullptr && ws_size >= (size_t)N * sizeof(vf4)) {
        vf4* pos4 = (vf4*)d_ws;
        const int pgrid = (N + BLOCK - 1) / BLOCK;
        pack_pos_batch<<<pgrid, BLOCK, 0, stream>>>(pos, batch, pos4, N);
        edge_encoding_kernel<true><<<grid, BLOCK, 0, stream>>>(
            pos, pos4, cells, eidx, pidx, batch, out, E);
    } else {
        edge_encoding_kernel<false><<<grid, BLOCK, 0, stream>>>(
            pos, nullptr, cells, eidx, pidx, batch, out, E);
    }
}